// Round 3
// baseline (337.723 us; speedup 1.0000x reference)
//
#include <hip/hip_runtime.h>

#define DEV __device__ __forceinline__

typedef unsigned short u16;
typedef short bf16x8 __attribute__((ext_vector_type(8)));
typedef float f32x4 __attribute__((ext_vector_type(4)));

// ---- problem constants (match reference) ----
#define BB    32
#define NOBJ  16
#define NREL  64
#define CCH   1024
#define FHW   50
#define HW    2500      // 50*50
#define NROI  512       // BB*NOBJ
#define MROWS 25088     // NROI*49  (= 196*128 = 98*256)
#define D1    1024
#define D2    512

DEV u16 f2bf(float f) {
  unsigned u = __float_as_uint(f);
  unsigned r = (u + 0x7FFFu + ((u >> 16) & 1u)) >> 16;
  return (u16)r;
}
DEV float bf2f(u16 h) { return __uint_as_float((unsigned)h << 16); }
DEV unsigned pk(float lo, float hi) { return (unsigned)f2bf(lo) | ((unsigned)f2bf(hi) << 16); }

using gvoid = __attribute__((address_space(1))) const void;
using svoid = __attribute__((address_space(3))) void;
DEV void gl_lds16(const void* g, void* s) {
  __builtin_amdgcn_global_load_lds((gvoid*)g, (svoid*)s, 16, 0, 0);
}

// ---------------- transpose + cast f32 -> bf16 ----------------
__global__ __launch_bounds__(256) void k_transpose_cast(
    const float* __restrict__ in, u16* __restrict__ out, int R, int C) {
  __shared__ float tile[64][65];
  const int b = blockIdx.z;
  const int c0 = blockIdx.x * 64;
  const int r0 = blockIdx.y * 64;
  const float* inb = in + (size_t)b * R * C;
  u16* outb = out + (size_t)b * R * C;
  const int t = threadIdx.x;
  {
    const int rr = t >> 4;
    const int cq = (t & 15) * 4;
#pragma unroll
    for (int it = 0; it < 4; ++it) {
      int rl = rr + it * 16;
      int r = r0 + rl;
      int c = c0 + cq;
      if (c + 3 < C) {
        float4 v = *reinterpret_cast<const float4*>(&inb[(size_t)r * C + c]);
        tile[rl][cq + 0] = v.x; tile[rl][cq + 1] = v.y;
        tile[rl][cq + 2] = v.z; tile[rl][cq + 3] = v.w;
      } else {
#pragma unroll
        for (int j = 0; j < 4; ++j)
          tile[rl][cq + j] = (c + j < C) ? inb[(size_t)r * C + c + j] : 0.f;
      }
    }
  }
  __syncthreads();
  {
    const int c = t >> 2;
    const int rch = (t & 3) * 8;
    if (c0 + c < C) {
#pragma unroll
      for (int half = 0; half < 2; ++half) {
        int rb = rch + half * 32;
        uint4 o;
        o.x = pk(tile[rb + 0][c], tile[rb + 1][c]);
        o.y = pk(tile[rb + 2][c], tile[rb + 3][c]);
        o.z = pk(tile[rb + 4][c], tile[rb + 5][c]);
        o.w = pk(tile[rb + 6][c], tile[rb + 7][c]);
        *reinterpret_cast<uint4*>(&outb[(size_t)(c0 + c) * R + r0 + rb]) = o;
      }
    }
  }
}

// ---------------- ROI align (fast path, fmT gather) ----------------
DEV void acc8(const u16* p, float w, float* a) {
  uint4 v = *reinterpret_cast<const uint4*>(p);
  a[0] = fmaf(w, bf2f((u16)(v.x & 0xffffu)), a[0]);
  a[1] = fmaf(w, bf2f((u16)(v.x >> 16)), a[1]);
  a[2] = fmaf(w, bf2f((u16)(v.y & 0xffffu)), a[2]);
  a[3] = fmaf(w, bf2f((u16)(v.y >> 16)), a[3]);
  a[4] = fmaf(w, bf2f((u16)(v.z & 0xffffu)), a[4]);
  a[5] = fmaf(w, bf2f((u16)(v.z >> 16)), a[5]);
  a[6] = fmaf(w, bf2f((u16)(v.w & 0xffffu)), a[6]);
  a[7] = fmaf(w, bf2f((u16)(v.w >> 16)), a[7]);
}

__global__ __launch_bounds__(128) void k_roi_fast(
    const u16* __restrict__ fmT, const float* __restrict__ bboxes,
    const int* __restrict__ pfw, const int* __restrict__ pfh,
    u16* __restrict__ Aout) {
  const int r = blockIdx.x;
  const int py = blockIdx.y;
  const int b = r >> 4;
  const int t = threadIdx.x;
  const int c0 = t * 8;

  __shared__ int s_lo[2][14], s_hi[2][14];
  __shared__ float s_w0[2][14], s_w1[2][14], s_v[2][14];

  int axis = -1, i = 0;
  if (t < 14) { axis = 0; i = t; }
  else if (t >= 64 && t < 78) { axis = 1; i = t - 64; }
  if (axis >= 0) {
    float fwf = (float)pfw[0], fhf = (float)pfh[0];
    float hs = (float)FHW / fwf;
    float wsc = (float)FHW / fhf;
    float v1 = bboxes[r * 4 + (axis == 0 ? 1 : 0)] * (axis == 0 ? hs : wsc);
    float v2 = bboxes[r * 4 + (axis == 0 ? 3 : 2)] * (axis == 0 ? hs : wsc);
    float ext = fmaxf(v2 - v1, 1.0f);
    float g = (float)(i >> 1) + ((i & 1) ? 0.75f : 0.25f);
    float coord = v1 + (ext / 7.0f) * g;
    float valid = (coord >= -1.0f && coord <= 50.0f) ? 1.0f : 0.0f;
    float cc = fmaxf(coord, 0.0f);
    int lo = (int)floorf(cc);
    bool edge = (lo >= FHW - 1);
    lo = min(lo, FHW - 1);
    int hi = min(lo + 1, FHW - 1);
    float l = edge ? 0.0f : (cc - (float)lo);
    s_lo[axis][i] = lo; s_hi[axis][i] = hi;
    s_w0[axis][i] = 1.0f - l; s_w1[axis][i] = l; s_v[axis][i] = valid;
  }
  __syncthreads();

  const u16* bt = fmT + (size_t)b * HW * CCH + c0;

  for (int px = 0; px < 7; ++px) {
    float a[8] = {};
#pragma unroll
    for (int s = 0; s < 4; ++s) {
      int sy = s >> 1, sx = s & 1;
      int iy = py * 2 + sy, jx = px * 2 + sx;
      int yl = s_lo[0][iy], yh = s_hi[0][iy];
      int xl = s_lo[1][jx], xh = s_hi[1][jx];
      float vv = s_v[0][iy] * s_v[1][jx];
      float wy0 = s_w0[0][iy] * vv, wy1 = s_w1[0][iy] * vv;
      float wx0 = s_w0[1][jx], wx1 = s_w1[1][jx];
      acc8(bt + (size_t)(yl * FHW + xl) * CCH, wy0 * wx0, a);
      acc8(bt + (size_t)(yl * FHW + xh) * CCH, wy0 * wx1, a);
      acc8(bt + (size_t)(yh * FHW + xl) * CCH, wy1 * wx0, a);
      acc8(bt + (size_t)(yh * FHW + xh) * CCH, wy1 * wx1, a);
    }
    u16* dst = Aout + (size_t)(r * 49 + py * 7 + px) * CCH + c0;
    uint4 o;
    o.x = pk(a[0] * 0.25f, a[1] * 0.25f);
    o.y = pk(a[2] * 0.25f, a[3] * 0.25f);
    o.z = pk(a[4] * 0.25f, a[5] * 0.25f);
    o.w = pk(a[6] * 0.25f, a[7] * 0.25f);
    *reinterpret_cast<uint4*>(dst) = o;
  }
}

// ---------------- GEMM v2: 256x256 tile, BK=64, 8 waves, 8-phase ----------------
// A: (M,K) bf16 row-major.  Bt: (N,K) bf16 row-major.  Out = relu(A@Bt^T + bias).
// LDS 128 KiB dynamic: buf b at b*65536; A-tile [256][64] at +0, B-tile at +32768.
// st_16x32 swizzle on byte offsets: P = L ^ (((L>>9)&1)<<5)  (involution).
template <int K, int N, int OBF>
__global__ __launch_bounds__(512, 2) void k_gemm8(
    const u16* __restrict__ A, const u16* __restrict__ Bt,
    const float* __restrict__ bias, void* __restrict__ Out) {
  extern __shared__ char smem[];
  const int t = threadIdx.x;
  const int lane = t & 63;
  const int wid = t >> 6;
  const int wr = wid >> 2, wc = wid & 3;   // 2M x 4N wave grid

  // bijective XCD swizzle (m204)
  const int nwg = (int)gridDim.x;
  const int orig = (int)blockIdx.x;
  const int xcd = orig & 7, q = nwg >> 3, r = nwg & 7;
  const int swz = (xcd < r ? xcd * (q + 1) : r * (q + 1) + (xcd - r) * q) + (orig >> 3);
  constexpr int GN = N / 256;
  const size_t m0 = (size_t)(swz / GN) * 256;
  const int n0 = (swz % GN) * 256;

  constexpr int NKT = K / 64;

  f32x4 acc[8][4] = {};

  // stage one quarter (2 x global_load_lds / thread) of a K-tile into buffer `bufb`
  auto stage_quarter = [&](int bufb, int k0, int qt) {
    const u16* src = (qt < 2) ? A : Bt;
    const size_t rbase = (qt < 2) ? m0 : (size_t)n0;
    const int regionBase = bufb + ((qt < 2) ? 0 : 32768);
    const int half = qt & 1;
#pragma unroll
    for (int c = 0; c < 2; ++c) {
      int P = half * 16384 + c * 8192 + t * 16;        // physical (linear dest)
      int L = P ^ (((P >> 9) & 1) << 5);               // logical source offset
      int row = L >> 7;
      int kb = L & 127;
      gl_lds16(src + (rbase + row) * (size_t)K + k0 + (kb >> 1),
               smem + regionBase + P);
    }
  };
  auto lda = [&](int bufb, int mrow, int kc) -> bf16x8 {
    int L = mrow * 128 + kc * 2;
    int P = L ^ (((L >> 9) & 1) << 5);
    return *reinterpret_cast<const bf16x8*>(smem + bufb + P);
  };
  auto ldb = [&](int bufb, int nrow, int kc) -> bf16x8 {
    int L = nrow * 128 + kc * 2;
    int P = L ^ (((L >> 9) & 1) << 5);
    return *reinterpret_cast<const bf16x8*>(smem + bufb + 32768 + P);
  };

  // prologue: stage tile 0 -> buf0, tile 1 -> buf1; drain; barrier
#pragma unroll
  for (int qt = 0; qt < 4; ++qt) stage_quarter(0, 0, qt);
  if (NKT > 1) {
#pragma unroll
    for (int qt = 0; qt < 4; ++qt) stage_quarter(65536, 64, qt);
  }
  asm volatile("s_waitcnt vmcnt(0)" ::: "memory");
  __builtin_amdgcn_s_barrier();

  for (int tt = 0; tt < NKT; ++tt) {
    const int bb = (tt & 1) ? 65536 : 0;
    const int nb = bb ^ 65536;
    const bool do_stage = (tt >= 1) && (tt + 1 < NKT);
    const int k0n = (tt + 1) * 64;
#pragma unroll
    for (int p = 0; p < 4; ++p) {
      const int qm = p >> 1, qn = p & 1;   // C-quadrant: 64 rows x 32 cols
      bf16x8 av[2][4], bv[2][2];
#pragma unroll
      for (int ks = 0; ks < 2; ++ks) {
        const int kc = ks * 32 + (lane >> 4) * 8;
#pragma unroll
        for (int m = 0; m < 4; ++m)
          av[ks][m] = lda(bb, wr * 128 + qm * 64 + m * 16 + (lane & 15), kc);
#pragma unroll
        for (int n = 0; n < 2; ++n)
          bv[ks][n] = ldb(bb, wc * 64 + qn * 32 + n * 16 + (lane & 15), kc);
      }
      if (do_stage && p < 2) {           // issue next tile early (phases 0,1)
        stage_quarter(nb, k0n, p * 2 + 0);
        stage_quarter(nb, k0n, p * 2 + 1);
      }
      __builtin_amdgcn_s_barrier();
      __builtin_amdgcn_s_setprio(1);
#pragma unroll
      for (int ks = 0; ks < 2; ++ks)
#pragma unroll
        for (int m = 0; m < 4; ++m)
#pragma unroll
          for (int n = 0; n < 2; ++n)
            asm("v_mfma_f32_16x16x32_bf16 %0, %1, %2, %0"
                : "+v"(acc[qm * 4 + m][qn * 2 + n])
                : "v"(av[ks][m]), "v"(bv[ks][n]));
      __builtin_amdgcn_s_setprio(0);
      if (p == 3 && tt + 1 < NKT)
        asm volatile("s_waitcnt vmcnt(0)" ::: "memory");  // next tile landed
      __builtin_amdgcn_s_barrier();
    }
  }
  asm volatile("s_nop 7\n\ts_nop 7\n\ts_nop 7" ::);

#pragma unroll
  for (int nf = 0; nf < 4; ++nf) {
    const int col = n0 + wc * 64 + nf * 16 + (lane & 15);
    const float bbv = bias[col];
#pragma unroll
    for (int mf = 0; mf < 8; ++mf) {
      const size_t row0 = m0 + wr * 128 + mf * 16 + (lane >> 4) * 4;
#pragma unroll
      for (int qq = 0; qq < 4; ++qq) {
        float v = fmaxf(acc[mf][nf][qq] + bbv, 0.0f);
        if (OBF) ((u16*)Out)[(row0 + qq) * N + col] = f2bf(v);
        else     ((float*)Out)[(row0 + qq) * N + col] = v;
      }
    }
  }
}

// ---------------- GEMM fallback (m97 structure, proven) ----------------
template <int K, int N, int OBF>
__global__ __launch_bounds__(256) void k_gemm(
    const u16* __restrict__ A, const u16* __restrict__ Bt,
    const float* __restrict__ bias, void* __restrict__ Out) {
  __shared__ alignas(16) u16 As[128 * 32];
  __shared__ alignas(16) u16 Bs[128 * 32];
  const int t = threadIdx.x;
  const int lane = t & 63, w = t >> 6;
  const int wr = w >> 1, wc = w & 1;
  const int NT = N / 128;
  const int bid = blockIdx.x;
  const int chunk = (int)(gridDim.x >> 3);
  const int swz = (bid & 7) * chunk + (bid >> 3);
  const size_t m0 = (size_t)(swz / NT) * 128;
  const int n0 = (swz % NT) * 128;
  f32x4 acc[4][4] = {};
  const int srow = t >> 2;
  const int skc = (t & 3) * 8;
  for (int ks = 0; ks < K / 32; ++ks) {
    const int k0 = ks * 32;
    if (ks) __syncthreads();
    gl_lds16(A + (m0 + srow) * K + k0 + skc, &As[(size_t)t * 8]);
    gl_lds16(A + (m0 + 64 + srow) * K + k0 + skc, &As[(size_t)(t + 256) * 8]);
    gl_lds16(Bt + (size_t)(n0 + srow) * K + k0 + skc, &Bs[(size_t)t * 8]);
    gl_lds16(Bt + (size_t)(n0 + 64 + srow) * K + k0 + skc, &Bs[(size_t)(t + 256) * 8]);
    __syncthreads();
    const int koff = (lane >> 4) * 8;
    bf16x8 av[4], bv[4];
#pragma unroll
    for (int m = 0; m < 4; ++m)
      av[m] = *reinterpret_cast<const bf16x8*>(&As[(wr * 64 + m * 16 + (lane & 15)) * 32 + koff]);
#pragma unroll
    for (int n = 0; n < 4; ++n)
      bv[n] = *reinterpret_cast<const bf16x8*>(&Bs[(wc * 64 + n * 16 + (lane & 15)) * 32 + koff]);
#pragma unroll
    for (int m = 0; m < 4; ++m)
#pragma unroll
      for (int n = 0; n < 4; ++n)
        asm("v_mfma_f32_16x16x32_bf16 %0, %1, %2, %0"
            : "+v"(acc[m][n]) : "v"(av[m]), "v"(bv[n]));
  }
  asm volatile("s_nop 7\n\ts_nop 7\n\ts_nop 7" ::);
#pragma unroll
  for (int n = 0; n < 4; ++n) {
    int col = n0 + wc * 64 + n * 16 + (lane & 15);
    float bb = bias[col];
#pragma unroll
    for (int m = 0; m < 4; ++m) {
      size_t row0 = m0 + wr * 64 + m * 16 + (lane >> 4) * 4;
#pragma unroll
      for (int qq = 0; qq < 4; ++qq) {
        float v = fmaxf(acc[m][n][qq] + bb, 0.0f);
        if (OBF) ((u16*)Out)[(row0 + qq) * N + col] = f2bf(v);
        else     ((float*)Out)[(row0 + qq) * N + col] = v;
      }
    }
  }
}

// ---------------- mean over 49 bins (bf16 input) ----------------
__global__ __launch_bounds__(256) void k_mean(const u16* __restrict__ H2,
                                              float* __restrict__ feat) {
  const int r = blockIdx.x;
  const int c = threadIdx.x * 2;
  float s0 = 0.f, s1 = 0.f;
#pragma unroll
  for (int qq = 0; qq < 49; ++qq) {
    unsigned v = *reinterpret_cast<const unsigned*>(&H2[((size_t)r * 49 + qq) * D2 + c]);
    s0 += bf2f((u16)(v & 0xffffu));
    s1 += bf2f((u16)(v >> 16));
  }
  feat[(size_t)r * D2 + c] = s0 * (1.0f / 49.0f);
  feat[(size_t)r * D2 + c + 1] = s1 * (1.0f / 49.0f);
}

// ---------------- pair gather ----------------
__global__ __launch_bounds__(256) void k_pairs(
    const float* __restrict__ feat, const int* __restrict__ num_obj,
    const int* __restrict__ pairs, float* __restrict__ out) {
  int r = blockIdx.x;
  int b = r >> 6;
  int off = 0;
  for (int i = 0; i < b; ++i) off += num_obj[i];
  int g0 = off + pairs[r * 2 + 0];
  int g1 = off + pairs[r * 2 + 1];
  for (int c = threadIdx.x; c < D2; c += 256) {
    out[(size_t)r * D2 + c] = 0.5f * (feat[(size_t)g0 * D2 + c] + feat[(size_t)g1 * D2 + c]);
  }
}

extern "C" void kernel_launch(void* const* d_in, const int* in_sizes, int n_in,
                              void* d_out, int out_size, void* d_ws, size_t ws_size,
                              hipStream_t stream) {
  const float* fmap = (const float*)d_in[0];
  const float* bboxes = (const float*)d_in[1];
  const int* num_obj = (const int*)d_in[2];
  const int* obj_pairs = (const int*)d_in[3];
  const int* pfw = (const int*)d_in[5];
  const int* pfh = (const int*)d_in[6];
  const float* W1 = (const float*)d_in[7];
  const float* b1 = (const float*)d_in[8];
  const float* W2 = (const float*)d_in[9];
  const float* b2 = (const float*)d_in[10];
  float* out = (float*)d_out;

  const size_t SZ_FMT = (size_t)BB * HW * CCH * 2;
  const size_t SZ_A   = (size_t)MROWS * D1 * 2;
  const size_t SZ_H1  = (size_t)MROWS * D1 * 2;
  const size_t SZ_W1B = (size_t)D1 * D1 * 2;
  const size_t SZ_W2B = (size_t)D1 * D2 * 2;
  const size_t SZ_FEAT = (size_t)NROI * D2 * 4;

  char* ws = (char*)d_ws;
  u16 *fmT, *A, *H1, *W1b, *W2b, *H2b;
  float *feat;
  fmT = (u16*)ws;
  A = (u16*)(ws + SZ_FMT);
  H1 = (u16*)(ws + SZ_FMT + SZ_A);
  W1b = (u16*)(ws + SZ_FMT + SZ_A + SZ_H1);
  W2b = (u16*)(ws + SZ_FMT + SZ_A + SZ_H1 + SZ_W1B);
  feat = (float*)(ws + SZ_FMT + SZ_A + SZ_H1 + SZ_W1B + SZ_W2B);
  H2b = fmT;  // fmT dead after ROI align

  // enable 128 KiB dynamic LDS for the 8-phase GEMMs (host-side, capture-safe)
  bool useNew = true;
  if (hipFuncSetAttribute((const void*)k_gemm8<D1, D1, 1>,
                          hipFuncAttributeMaxDynamicSharedMemorySize, 131072) != hipSuccess)
    useNew = false;
  if (hipFuncSetAttribute((const void*)k_gemm8<D1, D2, 1>,
                          hipFuncAttributeMaxDynamicSharedMemorySize, 131072) != hipSuccess)
    useNew = false;

  // weight transposes (K,N)->(N,K) bf16
  k_transpose_cast<<<dim3(16, 16, 1), 256, 0, stream>>>(W1, W1b, D1, D1);
  k_transpose_cast<<<dim3(8, 16, 1), 256, 0, stream>>>(W2, W2b, D1, D2);

  // fmap (B, C=1024, HW=2500) -> (B, HW, C) bf16
  k_transpose_cast<<<dim3(40, 16, BB), 256, 0, stream>>>(fmap, fmT, CCH, HW);
  k_roi_fast<<<dim3(NROI, 7), 128, 0, stream>>>(fmT, bboxes, pfw, pfh, A);

  if (useNew) {
    k_gemm8<D1, D1, 1><<<(MROWS / 256) * (D1 / 256), 512, 131072, stream>>>(A, W1b, b1, (void*)H1);
    k_gemm8<D1, D2, 1><<<(MROWS / 256) * (D2 / 256), 512, 131072, stream>>>(H1, W2b, b2, (void*)H2b);
  } else {
    k_gemm<D1, D1, 1><<<(MROWS / 128) * (D1 / 128), 256, 0, stream>>>(A, W1b, b1, (void*)H1);
    k_gemm<D1, D2, 1><<<(MROWS / 128) * (D2 / 128), 256, 0, stream>>>(H1, W2b, b2, (void*)H2b);
  }
  k_mean<<<NROI, 256, 0, stream>>>(H2b, feat);
  k_pairs<<<BB * NREL, 256, 0, stream>>>(feat, num_obj, obj_pairs, out);
}

// Round 4
// 321.227 us; speedup vs baseline: 1.0514x; 1.0514x over previous
//
#include <hip/hip_runtime.h>

#define DEV __device__ __forceinline__

typedef unsigned short u16;
typedef short bf16x8 __attribute__((ext_vector_type(8)));
typedef float f32x4 __attribute__((ext_vector_type(4)));

// ---- problem constants (match reference) ----
#define BB    32
#define NOBJ  16
#define NREL  64
#define CCH   1024
#define FHW   50
#define HW    2500      // 50*50
#define NROI  512       // BB*NOBJ
#define MROWS 25088     // NROI*49  (= 196*128 = 98*256)
#define D1    1024
#define D2    512

DEV u16 f2bf(float f) {
  unsigned u = __float_as_uint(f);
  unsigned r = (u + 0x7FFFu + ((u >> 16) & 1u)) >> 16;
  return (u16)r;
}
DEV float bf2f(u16 h) { return __uint_as_float((unsigned)h << 16); }
DEV unsigned pk(float lo, float hi) { return (unsigned)f2bf(lo) | ((unsigned)f2bf(hi) << 16); }

using gvoid = __attribute__((address_space(1))) const void;
using svoid = __attribute__((address_space(3))) void;
DEV void gl_lds16(const void* g, void* s) {
  __builtin_amdgcn_global_load_lds((gvoid*)g, (svoid*)s, 16, 0, 0);
}

// ---------------- transpose + cast f32 -> bf16 ----------------
__global__ __launch_bounds__(256) void k_transpose_cast(
    const float* __restrict__ in, u16* __restrict__ out, int R, int C) {
  __shared__ float tile[64][65];
  const int b = blockIdx.z;
  const int c0 = blockIdx.x * 64;
  const int r0 = blockIdx.y * 64;
  const float* inb = in + (size_t)b * R * C;
  u16* outb = out + (size_t)b * R * C;
  const int t = threadIdx.x;
  {
    const int rr = t >> 4;
    const int cq = (t & 15) * 4;
#pragma unroll
    for (int it = 0; it < 4; ++it) {
      int rl = rr + it * 16;
      int r = r0 + rl;
      int c = c0 + cq;
      if (c + 3 < C) {
        float4 v = *reinterpret_cast<const float4*>(&inb[(size_t)r * C + c]);
        tile[rl][cq + 0] = v.x; tile[rl][cq + 1] = v.y;
        tile[rl][cq + 2] = v.z; tile[rl][cq + 3] = v.w;
      } else {
#pragma unroll
        for (int j = 0; j < 4; ++j)
          tile[rl][cq + j] = (c + j < C) ? inb[(size_t)r * C + c + j] : 0.f;
      }
    }
  }
  __syncthreads();
  {
    const int c = t >> 2;
    const int rch = (t & 3) * 8;
    if (c0 + c < C) {
#pragma unroll
      for (int half = 0; half < 2; ++half) {
        int rb = rch + half * 32;
        uint4 o;
        o.x = pk(tile[rb + 0][c], tile[rb + 1][c]);
        o.y = pk(tile[rb + 2][c], tile[rb + 3][c]);
        o.z = pk(tile[rb + 4][c], tile[rb + 5][c]);
        o.w = pk(tile[rb + 6][c], tile[rb + 7][c]);
        *reinterpret_cast<uint4*>(&outb[(size_t)(c0 + c) * R + r0 + rb]) = o;
      }
    }
  }
}

// ---------------- ROI align (fast path, fmT gather) ----------------
DEV void acc8(const u16* p, float w, float* a) {
  uint4 v = *reinterpret_cast<const uint4*>(p);
  a[0] = fmaf(w, bf2f((u16)(v.x & 0xffffu)), a[0]);
  a[1] = fmaf(w, bf2f((u16)(v.x >> 16)), a[1]);
  a[2] = fmaf(w, bf2f((u16)(v.y & 0xffffu)), a[2]);
  a[3] = fmaf(w, bf2f((u16)(v.y >> 16)), a[3]);
  a[4] = fmaf(w, bf2f((u16)(v.z & 0xffffu)), a[4]);
  a[5] = fmaf(w, bf2f((u16)(v.z >> 16)), a[5]);
  a[6] = fmaf(w, bf2f((u16)(v.w & 0xffffu)), a[6]);
  a[7] = fmaf(w, bf2f((u16)(v.w >> 16)), a[7]);
}

__global__ __launch_bounds__(128) void k_roi_fast(
    const u16* __restrict__ fmT, const float* __restrict__ bboxes,
    const int* __restrict__ pfw, const int* __restrict__ pfh,
    u16* __restrict__ Aout) {
  const int r = blockIdx.x;
  const int py = blockIdx.y;
  const int b = r >> 4;
  const int t = threadIdx.x;
  const int c0 = t * 8;

  __shared__ int s_lo[2][14], s_hi[2][14];
  __shared__ float s_w0[2][14], s_w1[2][14], s_v[2][14];

  int axis = -1, i = 0;
  if (t < 14) { axis = 0; i = t; }
  else if (t >= 64 && t < 78) { axis = 1; i = t - 64; }
  if (axis >= 0) {
    float fwf = (float)pfw[0], fhf = (float)pfh[0];
    float hs = (float)FHW / fwf;
    float wsc = (float)FHW / fhf;
    float v1 = bboxes[r * 4 + (axis == 0 ? 1 : 0)] * (axis == 0 ? hs : wsc);
    float v2 = bboxes[r * 4 + (axis == 0 ? 3 : 2)] * (axis == 0 ? hs : wsc);
    float ext = fmaxf(v2 - v1, 1.0f);
    float g = (float)(i >> 1) + ((i & 1) ? 0.75f : 0.25f);
    float coord = v1 + (ext / 7.0f) * g;
    float valid = (coord >= -1.0f && coord <= 50.0f) ? 1.0f : 0.0f;
    float cc = fmaxf(coord, 0.0f);
    int lo = (int)floorf(cc);
    bool edge = (lo >= FHW - 1);
    lo = min(lo, FHW - 1);
    int hi = min(lo + 1, FHW - 1);
    float l = edge ? 0.0f : (cc - (float)lo);
    s_lo[axis][i] = lo; s_hi[axis][i] = hi;
    s_w0[axis][i] = 1.0f - l; s_w1[axis][i] = l; s_v[axis][i] = valid;
  }
  __syncthreads();

  const u16* bt = fmT + (size_t)b * HW * CCH + c0;

  for (int px = 0; px < 7; ++px) {
    float a[8] = {};
#pragma unroll
    for (int s = 0; s < 4; ++s) {
      int sy = s >> 1, sx = s & 1;
      int iy = py * 2 + sy, jx = px * 2 + sx;
      int yl = s_lo[0][iy], yh = s_hi[0][iy];
      int xl = s_lo[1][jx], xh = s_hi[1][jx];
      float vv = s_v[0][iy] * s_v[1][jx];
      float wy0 = s_w0[0][iy] * vv, wy1 = s_w1[0][iy] * vv;
      float wx0 = s_w0[1][jx], wx1 = s_w1[1][jx];
      acc8(bt + (size_t)(yl * FHW + xl) * CCH, wy0 * wx0, a);
      acc8(bt + (size_t)(yl * FHW + xh) * CCH, wy0 * wx1, a);
      acc8(bt + (size_t)(yh * FHW + xl) * CCH, wy1 * wx0, a);
      acc8(bt + (size_t)(yh * FHW + xh) * CCH, wy1 * wx1, a);
    }
    u16* dst = Aout + (size_t)(r * 49 + py * 7 + px) * CCH + c0;
    uint4 o;
    o.x = pk(a[0] * 0.25f, a[1] * 0.25f);
    o.y = pk(a[2] * 0.25f, a[3] * 0.25f);
    o.z = pk(a[4] * 0.25f, a[5] * 0.25f);
    o.w = pk(a[6] * 0.25f, a[7] * 0.25f);
    *reinterpret_cast<uint4*>(dst) = o;
  }
}

// ---------------- GEMM v2: 256x256 tile, BK=64, 8 waves, 4-phase w/ reg reuse ---
// A: (M,K) bf16 row-major.  Bt: (N,K) bf16 row-major.  Out = relu(A@Bt^T + bias).
// LDS 128 KiB dynamic: buf b at b*65536; A-tile [256][64] at +0, B-tile at +32768.
// st_16x32 swizzle on byte offsets: P = L ^ (((L>>9)&1)<<5)  (involution).
// Per-phase ds_reads: 12/4/8/0 (register reuse) = 24 b128/K-tile/wave (was 48).
template <int K, int N, int OBF>
__global__ __launch_bounds__(512, 2) void k_gemm8(
    const u16* __restrict__ A, const u16* __restrict__ Bt,
    const float* __restrict__ bias, void* __restrict__ Out) {
  extern __shared__ char smem[];
  const int t = threadIdx.x;
  const int lane = t & 63;
  const int wid = t >> 6;
  const int wr = wid >> 2, wc = wid & 3;   // 2M x 4N wave grid

  // bijective XCD swizzle (m204)
  const int nwg = (int)gridDim.x;
  const int orig = (int)blockIdx.x;
  const int xcd = orig & 7, q = nwg >> 3, r = nwg & 7;
  const int swz = (xcd < r ? xcd * (q + 1) : r * (q + 1) + (xcd - r) * q) + (orig >> 3);
  constexpr int GN = N / 256;
  const size_t m0 = (size_t)(swz / GN) * 256;
  const int n0 = (swz % GN) * 256;

  constexpr int NKT = K / 64;

  f32x4 acc[8][4] = {};

  // one half-tile stage = 2 x global_load_lds / thread (8 KB x 2 = 16 KB)
  auto stage_quarter = [&](int bufb, int k0, int qt) {
    const u16* src = (qt < 2) ? A : Bt;
    const size_t rbase = (qt < 2) ? m0 : (size_t)n0;
    const int regionBase = bufb + ((qt < 2) ? 0 : 32768);
    const int half = qt & 1;
#pragma unroll
    for (int c = 0; c < 2; ++c) {
      int P = half * 16384 + c * 8192 + t * 16;        // physical (linear dest)
      int L = P ^ (((P >> 9) & 1) << 5);               // logical source offset
      int row = L >> 7;
      int kb = L & 127;
      gl_lds16(src + (rbase + row) * (size_t)K + k0 + (kb >> 1),
               smem + regionBase + P);
    }
  };
  auto lda = [&](int bufb, int mrow, int kc) -> bf16x8 {
    int L = mrow * 128 + kc * 2;
    int P = L ^ (((L >> 9) & 1) << 5);
    return *reinterpret_cast<const bf16x8*>(smem + bufb + P);
  };
  auto ldb = [&](int bufb, int nrow, int kc) -> bf16x8 {
    int L = nrow * 128 + kc * 2;
    int P = L ^ (((L >> 9) & 1) << 5);
    return *reinterpret_cast<const bf16x8*>(smem + bufb + 32768 + P);
  };

  // prologue: stage tile 0 -> buf0, tile 1 -> buf1; wait tile0; barrier
#pragma unroll
  for (int qt = 0; qt < 4; ++qt) stage_quarter(0, 0, qt);
  if (NKT > 1) {
#pragma unroll
    for (int qt = 0; qt < 4; ++qt) stage_quarter(65536, 64, qt);
    asm volatile("s_waitcnt vmcnt(8)" ::: "memory");
  } else {
    asm volatile("s_waitcnt vmcnt(0)" ::: "memory");
  }
  __builtin_amdgcn_s_barrier();

  bf16x8 av[2][4];      // current qm A-fragments
  bf16x8 bv[2][2][2];   // both qn B-fragments [qn][ks][n]

  for (int tt = 0; tt < NKT; ++tt) {
    const int bb = (tt & 1) ? 65536 : 0;
    const int nb = bb ^ 65536;
    const bool do_stage = (tt >= 1) && (tt + 1 < NKT);
    const int k0n = (tt + 1) * 64;

#define LOADA(qm_)                                                             \
  _Pragma("unroll")                                                            \
  for (int ks = 0; ks < 2; ++ks) {                                             \
    const int kc = ks * 32 + (lane >> 4) * 8;                                  \
    _Pragma("unroll")                                                          \
    for (int m = 0; m < 4; ++m)                                                \
      av[ks][m] = lda(bb, wr * 128 + (qm_) * 64 + m * 16 + (lane & 15), kc);   \
  }
#define LOADB(qn_)                                                             \
  _Pragma("unroll")                                                            \
  for (int ks = 0; ks < 2; ++ks) {                                             \
    const int kc = ks * 32 + (lane >> 4) * 8;                                  \
    _Pragma("unroll")                                                          \
    for (int n = 0; n < 2; ++n)                                                \
      bv[qn_][ks][n] = ldb(bb, wc * 64 + (qn_) * 32 + n * 16 + (lane & 15), kc); \
  }
#define DOMFMA(qm_, qn_)                                                       \
  __builtin_amdgcn_s_barrier();                                                \
  __builtin_amdgcn_s_setprio(1);                                               \
  _Pragma("unroll")                                                            \
  for (int ks = 0; ks < 2; ++ks)                                               \
    _Pragma("unroll")                                                          \
    for (int m = 0; m < 4; ++m)                                                \
      _Pragma("unroll")                                                        \
      for (int n = 0; n < 2; ++n)                                              \
        asm("v_mfma_f32_16x16x32_bf16 %0, %1, %2, %0"                          \
            : "+v"(acc[(qm_) * 4 + m][(qn_) * 2 + n])                          \
            : "v"(av[ks][m]), "v"(bv[qn_][ks][n]));                            \
  __builtin_amdgcn_s_setprio(0);

    // phase 0: read A[0] (8) + B[0] (4); stage q0; MFMA quad (0,0)
    LOADA(0); LOADB(0);
    if (do_stage) stage_quarter(nb, k0n, 0);
    DOMFMA(0, 0);
    __builtin_amdgcn_s_barrier();

    // phase 1: read B[1] (4); stage q1; MFMA quad (0,1)  [A reused]
    LOADB(1);
    if (do_stage) stage_quarter(nb, k0n, 1);
    DOMFMA(0, 1);
    __builtin_amdgcn_s_barrier();

    // phase 2: read A[1] (8); stage q2; MFMA quad (1,0)  [B0 kept live]
    LOADA(1);
    if (do_stage) stage_quarter(nb, k0n, 2);
    DOMFMA(1, 0);
    __builtin_amdgcn_s_barrier();

    // phase 3: no reads; stage q3; MFMA quad (1,1)  [A1,B1 reused]
    if (do_stage) stage_quarter(nb, k0n, 3);
    DOMFMA(1, 1);
    if (tt + 1 < NKT)
      asm volatile("s_waitcnt vmcnt(0)" ::: "memory");  // next tile landed
    __builtin_amdgcn_s_barrier();

#undef LOADA
#undef LOADB
#undef DOMFMA
  }
  asm volatile("s_nop 7\n\ts_nop 7\n\ts_nop 7" ::);

#pragma unroll
  for (int nf = 0; nf < 4; ++nf) {
    const int col = n0 + wc * 64 + nf * 16 + (lane & 15);
    const float bbv = bias[col];
#pragma unroll
    for (int mf = 0; mf < 8; ++mf) {
      const size_t row0 = m0 + wr * 128 + mf * 16 + (lane >> 4) * 4;
#pragma unroll
      for (int qq = 0; qq < 4; ++qq) {
        float v = fmaxf(acc[mf][nf][qq] + bbv, 0.0f);
        if (OBF) ((u16*)Out)[(row0 + qq) * N + col] = f2bf(v);
        else     ((float*)Out)[(row0 + qq) * N + col] = v;
      }
    }
  }
}

// ---------------- GEMM fallback (m97 structure, proven) ----------------
template <int K, int N, int OBF>
__global__ __launch_bounds__(256) void k_gemm(
    const u16* __restrict__ A, const u16* __restrict__ Bt,
    const float* __restrict__ bias, void* __restrict__ Out) {
  __shared__ alignas(16) u16 As[128 * 32];
  __shared__ alignas(16) u16 Bs[128 * 32];
  const int t = threadIdx.x;
  const int lane = t & 63, w = t >> 6;
  const int wr = w >> 1, wc = w & 1;
  const int NT = N / 128;
  const int bid = blockIdx.x;
  const int chunk = (int)(gridDim.x >> 3);
  const int swz = (bid & 7) * chunk + (bid >> 3);
  const size_t m0 = (size_t)(swz / NT) * 128;
  const int n0 = (swz % NT) * 128;
  f32x4 acc[4][4] = {};
  const int srow = t >> 2;
  const int skc = (t & 3) * 8;
  for (int ks = 0; ks < K / 32; ++ks) {
    const int k0 = ks * 32;
    if (ks) __syncthreads();
    gl_lds16(A + (m0 + srow) * K + k0 + skc, &As[(size_t)t * 8]);
    gl_lds16(A + (m0 + 64 + srow) * K + k0 + skc, &As[(size_t)(t + 256) * 8]);
    gl_lds16(Bt + (size_t)(n0 + srow) * K + k0 + skc, &Bs[(size_t)t * 8]);
    gl_lds16(Bt + (size_t)(n0 + 64 + srow) * K + k0 + skc, &Bs[(size_t)(t + 256) * 8]);
    __syncthreads();
    const int koff = (lane >> 4) * 8;
    bf16x8 av[4], bv[4];
#pragma unroll
    for (int m = 0; m < 4; ++m)
      av[m] = *reinterpret_cast<const bf16x8*>(&As[(wr * 64 + m * 16 + (lane & 15)) * 32 + koff]);
#pragma unroll
    for (int n = 0; n < 4; ++n)
      bv[n] = *reinterpret_cast<const bf16x8*>(&Bs[(wc * 64 + n * 16 + (lane & 15)) * 32 + koff]);
#pragma unroll
    for (int m = 0; m < 4; ++m)
#pragma unroll
      for (int n = 0; n < 4; ++n)
        asm("v_mfma_f32_16x16x32_bf16 %0, %1, %2, %0"
            : "+v"(acc[m][n]) : "v"(av[m]), "v"(bv[n]));
  }
  asm volatile("s_nop 7\n\ts_nop 7\n\ts_nop 7" ::);
#pragma unroll
  for (int n = 0; n < 4; ++n) {
    int col = n0 + wc * 64 + n * 16 + (lane & 15);
    float bb = bias[col];
#pragma unroll
    for (int m = 0; m < 4; ++m) {
      size_t row0 = m0 + wr * 64 + m * 16 + (lane >> 4) * 4;
#pragma unroll
      for (int qq = 0; qq < 4; ++qq) {
        float v = fmaxf(acc[m][n][qq] + bb, 0.0f);
        if (OBF) ((u16*)Out)[(row0 + qq) * N + col] = f2bf(v);
        else     ((float*)Out)[(row0 + qq) * N + col] = v;
      }
    }
  }
}

// ---------------- mean over 49 bins (bf16 input) ----------------
__global__ __launch_bounds__(256) void k_mean(const u16* __restrict__ H2,
                                              float* __restrict__ feat) {
  const int r = blockIdx.x;
  const int c = threadIdx.x * 2;
  float s0 = 0.f, s1 = 0.f;
#pragma unroll
  for (int qq = 0; qq < 49; ++qq) {
    unsigned v = *reinterpret_cast<const unsigned*>(&H2[((size_t)r * 49 + qq) * D2 + c]);
    s0 += bf2f((u16)(v & 0xffffu));
    s1 += bf2f((u16)(v >> 16));
  }
  feat[(size_t)r * D2 + c] = s0 * (1.0f / 49.0f);
  feat[(size_t)r * D2 + c + 1] = s1 * (1.0f / 49.0f);
}

// ---------------- pair gather ----------------
__global__ __launch_bounds__(256) void k_pairs(
    const float* __restrict__ feat, const int* __restrict__ num_obj,
    const int* __restrict__ pairs, float* __restrict__ out) {
  int r = blockIdx.x;
  int b = r >> 6;
  int off = 0;
  for (int i = 0; i < b; ++i) off += num_obj[i];
  int g0 = off + pairs[r * 2 + 0];
  int g1 = off + pairs[r * 2 + 1];
  for (int c = threadIdx.x; c < D2; c += 256) {
    out[(size_t)r * D2 + c] = 0.5f * (feat[(size_t)g0 * D2 + c] + feat[(size_t)g1 * D2 + c]);
  }
}

extern "C" void kernel_launch(void* const* d_in, const int* in_sizes, int n_in,
                              void* d_out, int out_size, void* d_ws, size_t ws_size,
                              hipStream_t stream) {
  const float* fmap = (const float*)d_in[0];
  const float* bboxes = (const float*)d_in[1];
  const int* num_obj = (const int*)d_in[2];
  const int* obj_pairs = (const int*)d_in[3];
  const int* pfw = (const int*)d_in[5];
  const int* pfh = (const int*)d_in[6];
  const float* W1 = (const float*)d_in[7];
  const float* b1 = (const float*)d_in[8];
  const float* W2 = (const float*)d_in[9];
  const float* b2 = (const float*)d_in[10];
  float* out = (float*)d_out;

  const size_t SZ_FMT = (size_t)BB * HW * CCH * 2;
  const size_t SZ_A   = (size_t)MROWS * D1 * 2;
  const size_t SZ_H1  = (size_t)MROWS * D1 * 2;
  const size_t SZ_W1B = (size_t)D1 * D1 * 2;
  const size_t SZ_W2B = (size_t)D1 * D2 * 2;

  char* ws = (char*)d_ws;
  u16 *fmT, *A, *H1, *W1b, *W2b, *H2b;
  float *feat;
  fmT = (u16*)ws;
  A = (u16*)(ws + SZ_FMT);
  H1 = (u16*)(ws + SZ_FMT + SZ_A);
  W1b = (u16*)(ws + SZ_FMT + SZ_A + SZ_H1);
  W2b = (u16*)(ws + SZ_FMT + SZ_A + SZ_H1 + SZ_W1B);
  feat = (float*)(ws + SZ_FMT + SZ_A + SZ_H1 + SZ_W1B + SZ_W2B);
  H2b = fmT;  // fmT dead after ROI align

  // enable 128 KiB dynamic LDS for the 8-phase GEMMs (host-side, capture-safe)
  bool useNew = true;
  if (hipFuncSetAttribute((const void*)k_gemm8<D1, D1, 1>,
                          hipFuncAttributeMaxDynamicSharedMemorySize, 131072) != hipSuccess)
    useNew = false;
  if (hipFuncSetAttribute((const void*)k_gemm8<D1, D2, 1>,
                          hipFuncAttributeMaxDynamicSharedMemorySize, 131072) != hipSuccess)
    useNew = false;

  // weight transposes (K,N)->(N,K) bf16
  k_transpose_cast<<<dim3(16, 16, 1), 256, 0, stream>>>(W1, W1b, D1, D1);
  k_transpose_cast<<<dim3(8, 16, 1), 256, 0, stream>>>(W2, W2b, D1, D2);

  // fmap (B, C=1024, HW=2500) -> (B, HW, C) bf16
  k_transpose_cast<<<dim3(40, 16, BB), 256, 0, stream>>>(fmap, fmT, CCH, HW);
  k_roi_fast<<<dim3(NROI, 7), 128, 0, stream>>>(fmT, bboxes, pfw, pfh, A);

  if (useNew) {
    k_gemm8<D1, D1, 1><<<(MROWS / 256) * (D1 / 256), 512, 131072, stream>>>(A, W1b, b1, (void*)H1);
    k_gemm8<D1, D2, 1><<<(MROWS / 256) * (D2 / 256), 512, 131072, stream>>>(H1, W2b, b2, (void*)H2b);
  } else {
    k_gemm<D1, D1, 1><<<(MROWS / 128) * (D1 / 128), 256, 0, stream>>>(A, W1b, b1, (void*)H1);
    k_gemm<D1, D2, 1><<<(MROWS / 128) * (D2 / 128), 256, 0, stream>>>(H1, W2b, b2, (void*)H2b);
  }
  k_mean<<<NROI, 256, 0, stream>>>(H2b, feat);
  k_pairs<<<BB * NREL, 256, 0, stream>>>(feat, num_obj, obj_pairs, out);
}

// Round 5
// 277.483 us; speedup vs baseline: 1.2171x; 1.1576x over previous
//
#include <hip/hip_runtime.h>

#define DEV __device__ __forceinline__

typedef unsigned short u16;
typedef short bf16x8 __attribute__((ext_vector_type(8)));
typedef float f32x4 __attribute__((ext_vector_type(4)));

// ---- problem constants (match reference) ----
#define BB    32
#define NOBJ  16
#define NREL  64
#define CCH   1024
#define FHW   50
#define HW    2500      // 50*50
#define NROI  512       // BB*NOBJ
#define MROWS 25088     // NROI*49  (= 196*128)
#define D1    1024
#define D2    512

DEV u16 f2bf(float f) {
  unsigned u = __float_as_uint(f);
  unsigned r = (u + 0x7FFFu + ((u >> 16) & 1u)) >> 16;
  return (u16)r;
}
DEV float bf2f(u16 h) { return __uint_as_float((unsigned)h << 16); }
DEV unsigned pk(float lo, float hi) { return (unsigned)f2bf(lo) | ((unsigned)f2bf(hi) << 16); }

using gvoid = __attribute__((address_space(1))) const void;
using svoid = __attribute__((address_space(3))) void;
DEV void gl_lds16(const void* g, void* s) {
  __builtin_amdgcn_global_load_lds((gvoid*)g, (svoid*)s, 16, 0, 0);
}

// ---------------- transpose + cast f32 -> bf16 ----------------
// in: (batch, R, C) f32 ; out: (batch, C, R) bf16.  Requires R % 64 == 0.
__global__ __launch_bounds__(256) void k_transpose_cast(
    const float* __restrict__ in, u16* __restrict__ out, int R, int C) {
  __shared__ float tile[64][65];
  const int b = blockIdx.z;
  const int c0 = blockIdx.x * 64;
  const int r0 = blockIdx.y * 64;
  const float* inb = in + (size_t)b * R * C;
  u16* outb = out + (size_t)b * R * C;
  const int t = threadIdx.x;
  {
    const int rr = t >> 4;
    const int cq = (t & 15) * 4;
#pragma unroll
    for (int it = 0; it < 4; ++it) {
      int rl = rr + it * 16;
      int r = r0 + rl;
      int c = c0 + cq;
      if (c + 3 < C) {
        float4 v = *reinterpret_cast<const float4*>(&inb[(size_t)r * C + c]);
        tile[rl][cq + 0] = v.x; tile[rl][cq + 1] = v.y;
        tile[rl][cq + 2] = v.z; tile[rl][cq + 3] = v.w;
      } else {
#pragma unroll
        for (int j = 0; j < 4; ++j)
          tile[rl][cq + j] = (c + j < C) ? inb[(size_t)r * C + c + j] : 0.f;
      }
    }
  }
  __syncthreads();
  {
    const int c = t >> 2;
    const int rch = (t & 3) * 8;
    if (c0 + c < C) {
#pragma unroll
      for (int half = 0; half < 2; ++half) {
        int rb = rch + half * 32;
        uint4 o;
        o.x = pk(tile[rb + 0][c], tile[rb + 1][c]);
        o.y = pk(tile[rb + 2][c], tile[rb + 3][c]);
        o.z = pk(tile[rb + 4][c], tile[rb + 5][c]);
        o.w = pk(tile[rb + 6][c], tile[rb + 7][c]);
        *reinterpret_cast<uint4*>(&outb[(size_t)(c0 + c) * R + r0 + rb]) = o;
      }
    }
  }
}

// ---------------- ROI align with per-axis tap dedup ----------------
DEV void acc8(const u16* p, float w, float* a) {
  uint4 v = *reinterpret_cast<const uint4*>(p);
  a[0] = fmaf(w, bf2f((u16)(v.x & 0xffffu)), a[0]);
  a[1] = fmaf(w, bf2f((u16)(v.x >> 16)), a[1]);
  a[2] = fmaf(w, bf2f((u16)(v.y & 0xffffu)), a[2]);
  a[3] = fmaf(w, bf2f((u16)(v.y >> 16)), a[3]);
  a[4] = fmaf(w, bf2f((u16)(v.z & 0xffffu)), a[4]);
  a[5] = fmaf(w, bf2f((u16)(v.z >> 16)), a[5]);
  a[6] = fmaf(w, bf2f((u16)(v.w & 0xffffu)), a[6]);
  a[7] = fmaf(w, bf2f((u16)(v.w >> 16)), a[7]);
}

// Per (axis, bin): merge the 4 bilinear taps of the 2 sub-samples into a
// deduped (index, weight) list (weight includes validity). Typically 2-3 taps.
__global__ __launch_bounds__(128) void k_roi_fast(
    const u16* __restrict__ fmT, const float* __restrict__ bboxes,
    const int* __restrict__ pfw, const int* __restrict__ pfh,
    u16* __restrict__ Aout) {
  const int r = blockIdx.x;   // roi 0..511
  const int py = blockIdx.y;  // bin row 0..6
  const int b = r >> 4;
  const int t = threadIdx.x;
  const int c0 = t * 8;

  __shared__ int s_cnt[2][7];
  __shared__ int s_idx[2][7][4];
  __shared__ float s_wgt[2][7][4];

  int axis = -1, p = 0;
  if (t < 7) { axis = 0; p = t; }
  else if (t >= 64 && t < 71) { axis = 1; p = t - 64; }
  if (axis >= 0) {
    float fwf = (float)pfw[0], fhf = (float)pfh[0];
    // reference: im_height = frame_width, im_width = frame_height
    float hs = (float)FHW / fwf;
    float wsc = (float)FHW / fhf;
    float v1 = bboxes[r * 4 + (axis == 0 ? 1 : 0)] * (axis == 0 ? hs : wsc);
    float v2 = bboxes[r * 4 + (axis == 0 ? 3 : 2)] * (axis == 0 ? hs : wsc);
    float ext = fmaxf(v2 - v1, 1.0f);
    int idx[4]; float wgt[4]; int cnt = 0;
#pragma unroll
    for (int j = 0; j < 2; ++j) {
      float g = (float)p + (j ? 0.75f : 0.25f);
      float coord = v1 + (ext / 7.0f) * g;
      float valid = (coord >= -1.0f && coord <= 50.0f) ? 1.0f : 0.0f;
      float cc = fmaxf(coord, 0.0f);
      int lo = (int)floorf(cc);
      bool edge = (lo >= FHW - 1);
      lo = min(lo, FHW - 1);
      int hi = min(lo + 1, FHW - 1);
      float l = edge ? 0.0f : (cc - (float)lo);
      float pr_i[2]; int pr_x[2];
      pr_x[0] = lo; pr_i[0] = valid * (1.0f - l);
      pr_x[1] = hi; pr_i[1] = valid * l;
#pragma unroll
      for (int e = 0; e < 2; ++e) {
        if (pr_i[e] != 0.0f) {
          bool found = false;
          for (int q = 0; q < cnt; ++q)
            if (idx[q] == pr_x[e]) { wgt[q] += pr_i[e]; found = true; }
          if (!found) { idx[cnt] = pr_x[e]; wgt[cnt] = pr_i[e]; ++cnt; }
        }
      }
    }
    s_cnt[axis][p] = cnt;
#pragma unroll
    for (int q = 0; q < 4; ++q) {
      s_idx[axis][p][q] = (q < cnt) ? idx[q] : 0;
      s_wgt[axis][p][q] = (q < cnt) ? wgt[q] : 0.0f;
    }
  }
  __syncthreads();

  const u16* bt = fmT + (size_t)b * HW * CCH + c0;

  // hoist y-list for this py
  const int ycnt = s_cnt[0][py];
  int yrow[4]; float yw[4];
#pragma unroll
  for (int q = 0; q < 4; ++q) {
    yrow[q] = s_idx[0][py][q] * FHW;
    yw[q] = s_wgt[0][py][q];
  }

  for (int px = 0; px < 7; ++px) {
    const int xcnt = s_cnt[1][px];
    float a[8] = {};
    for (int jy = 0; jy < ycnt; ++jy) {
      const float wy = yw[jy];
      const int rowb = yrow[jy];
      for (int jx = 0; jx < xcnt; ++jx) {
        acc8(bt + (size_t)(rowb + s_idx[1][px][jx]) * CCH,
             wy * s_wgt[1][px][jx], a);
      }
    }
    u16* dst = Aout + (size_t)(r * 49 + py * 7 + px) * CCH + c0;
    uint4 o;
    o.x = pk(a[0] * 0.25f, a[1] * 0.25f);
    o.y = pk(a[2] * 0.25f, a[3] * 0.25f);
    o.z = pk(a[4] * 0.25f, a[5] * 0.25f);
    o.w = pk(a[6] * 0.25f, a[7] * 0.25f);
    *reinterpret_cast<uint4*>(dst) = o;
  }
}

// ---------------- GEMM (m97 structure, proven): Out = relu(A @ Bt^T + bias) ---
// A: (M,K) bf16 row-major.  Bt: (N,K) bf16 row-major.
// 128x128 tile, BK=32, 4 waves (2x2), 4x4 16x16 frags/wave.
// 1D grid, XCD-chunked swizzle (gridDim.x % 8 == 0), n-tile fastest.
template <int K, int N, int OBF>
__global__ __launch_bounds__(256) void k_gemm(
    const u16* __restrict__ A, const u16* __restrict__ Bt,
    const float* __restrict__ bias, void* __restrict__ Out) {
  __shared__ alignas(16) u16 As[128 * 32];
  __shared__ alignas(16) u16 Bs[128 * 32];
  const int t = threadIdx.x;
  const int lane = t & 63, w = t >> 6;
  const int wr = w >> 1, wc = w & 1;
  const int NT = N / 128;
  const int bid = blockIdx.x;
  const int chunk = (int)(gridDim.x >> 3);
  const int swz = (bid & 7) * chunk + (bid >> 3);
  const size_t m0 = (size_t)(swz / NT) * 128;
  const int n0 = (swz % NT) * 128;
  f32x4 acc[4][4] = {};
  const int srow = t >> 2;
  const int skc = (t & 3) * 8;
  for (int ks = 0; ks < K / 32; ++ks) {
    const int k0 = ks * 32;
    if (ks) __syncthreads();
    gl_lds16(A + (m0 + srow) * K + k0 + skc, &As[(size_t)t * 8]);
    gl_lds16(A + (m0 + 64 + srow) * K + k0 + skc, &As[(size_t)(t + 256) * 8]);
    gl_lds16(Bt + (size_t)(n0 + srow) * K + k0 + skc, &Bs[(size_t)t * 8]);
    gl_lds16(Bt + (size_t)(n0 + 64 + srow) * K + k0 + skc, &Bs[(size_t)(t + 256) * 8]);
    __syncthreads();
    const int koff = (lane >> 4) * 8;
    bf16x8 av[4], bv[4];
#pragma unroll
    for (int m = 0; m < 4; ++m)
      av[m] = *reinterpret_cast<const bf16x8*>(&As[(wr * 64 + m * 16 + (lane & 15)) * 32 + koff]);
#pragma unroll
    for (int n = 0; n < 4; ++n)
      bv[n] = *reinterpret_cast<const bf16x8*>(&Bs[(wc * 64 + n * 16 + (lane & 15)) * 32 + koff]);
#pragma unroll
    for (int m = 0; m < 4; ++m)
#pragma unroll
      for (int n = 0; n < 4; ++n)
        asm("v_mfma_f32_16x16x32_bf16 %0, %1, %2, %0"
            : "+v"(acc[m][n]) : "v"(av[m]), "v"(bv[n]));
  }
  asm volatile("s_nop 7\n\ts_nop 7\n\ts_nop 7" ::);
#pragma unroll
  for (int n = 0; n < 4; ++n) {
    int col = n0 + wc * 64 + n * 16 + (lane & 15);
    float bb = bias[col];
#pragma unroll
    for (int m = 0; m < 4; ++m) {
      size_t row0 = m0 + wr * 64 + m * 16 + (lane >> 4) * 4;
#pragma unroll
      for (int qq = 0; qq < 4; ++qq) {
        float v = fmaxf(acc[m][n][qq] + bb, 0.0f);
        if (OBF) ((u16*)Out)[(row0 + qq) * N + col] = f2bf(v);
        else     ((float*)Out)[(row0 + qq) * N + col] = v;
      }
    }
  }
}

// ---------------- mean over 49 bins (bf16 input) ----------------
__global__ __launch_bounds__(256) void k_mean(const u16* __restrict__ H2,
                                              float* __restrict__ feat) {
  const int r = blockIdx.x;
  const int c = threadIdx.x * 2;
  float s0 = 0.f, s1 = 0.f;
#pragma unroll
  for (int qq = 0; qq < 49; ++qq) {
    unsigned v = *reinterpret_cast<const unsigned*>(&H2[((size_t)r * 49 + qq) * D2 + c]);
    s0 += bf2f((u16)(v & 0xffffu));
    s1 += bf2f((u16)(v >> 16));
  }
  feat[(size_t)r * D2 + c] = s0 * (1.0f / 49.0f);
  feat[(size_t)r * D2 + c + 1] = s1 * (1.0f / 49.0f);
}

// ---------------- pair gather ----------------
__global__ __launch_bounds__(256) void k_pairs(
    const float* __restrict__ feat, const int* __restrict__ num_obj,
    const int* __restrict__ pairs, float* __restrict__ out) {
  int r = blockIdx.x;
  int b = r >> 6;
  int off = 0;
  for (int i = 0; i < b; ++i) off += num_obj[i];
  int g0 = off + pairs[r * 2 + 0];
  int g1 = off + pairs[r * 2 + 1];
  for (int c = threadIdx.x; c < D2; c += 256) {
    out[(size_t)r * D2 + c] = 0.5f * (feat[(size_t)g0 * D2 + c] + feat[(size_t)g1 * D2 + c]);
  }
}

extern "C" void kernel_launch(void* const* d_in, const int* in_sizes, int n_in,
                              void* d_out, int out_size, void* d_ws, size_t ws_size,
                              hipStream_t stream) {
  const float* fmap = (const float*)d_in[0];
  const float* bboxes = (const float*)d_in[1];
  const int* num_obj = (const int*)d_in[2];
  const int* obj_pairs = (const int*)d_in[3];
  const int* pfw = (const int*)d_in[5];
  const int* pfh = (const int*)d_in[6];
  const float* W1 = (const float*)d_in[7];
  const float* b1 = (const float*)d_in[8];
  const float* W2 = (const float*)d_in[9];
  const float* b2 = (const float*)d_in[10];
  float* out = (float*)d_out;

  const size_t SZ_FMT = (size_t)BB * HW * CCH * 2;
  const size_t SZ_A   = (size_t)MROWS * D1 * 2;
  const size_t SZ_H1  = (size_t)MROWS * D1 * 2;
  const size_t SZ_W1B = (size_t)D1 * D1 * 2;
  const size_t SZ_W2B = (size_t)D1 * D2 * 2;

  char* ws = (char*)d_ws;
  u16 *fmT, *A, *H1, *W1b, *W2b, *H2b;
  float *feat;
  fmT = (u16*)ws;
  A = (u16*)(ws + SZ_FMT);
  H1 = (u16*)(ws + SZ_FMT + SZ_A);
  W1b = (u16*)(ws + SZ_FMT + SZ_A + SZ_H1);
  W2b = (u16*)(ws + SZ_FMT + SZ_A + SZ_H1 + SZ_W1B);
  feat = (float*)(ws + SZ_FMT + SZ_A + SZ_H1 + SZ_W1B + SZ_W2B);
  H2b = fmT;  // fmT dead after ROI align

  // weight transposes (K,N)->(N,K) bf16
  k_transpose_cast<<<dim3(16, 16, 1), 256, 0, stream>>>(W1, W1b, D1, D1);
  k_transpose_cast<<<dim3(8, 16, 1), 256, 0, stream>>>(W2, W2b, D1, D2);

  // fmap (B, C=1024, HW=2500) -> (B, HW, C) bf16
  k_transpose_cast<<<dim3(40, 16, BB), 256, 0, stream>>>(fmap, fmT, CCH, HW);
  k_roi_fast<<<dim3(NROI, 7), 128, 0, stream>>>(fmT, bboxes, pfw, pfh, A);

  k_gemm<D1, D1, 1><<<(MROWS / 128) * (D1 / 128), 256, 0, stream>>>(A, W1b, b1, (void*)H1);
  k_gemm<D1, D2, 1><<<(MROWS / 128) * (D2 / 128), 256, 0, stream>>>(H1, W2b, b2, (void*)H2b);
  k_mean<<<NROI, 256, 0, stream>>>(H2b, feat);
  k_pairs<<<BB * NREL, 256, 0, stream>>>(feat, num_obj, obj_pairs, out);
}

// Round 6
// 269.792 us; speedup vs baseline: 1.2518x; 1.0285x over previous
//
#include <hip/hip_runtime.h>

#define DEV __device__ __forceinline__

typedef unsigned short u16;
typedef short bf16x8 __attribute__((ext_vector_type(8)));
typedef float f32x4 __attribute__((ext_vector_type(4)));

// ---- problem constants (match reference) ----
#define BB    32
#define NOBJ  16
#define NREL  64
#define CCH   1024
#define FHW   50
#define HW    2500      // 50*50
#define NROI  512       // BB*NOBJ
#define MROWS 25088     // NROI*49  (= 196*128)
#define D1    1024
#define D2    512

DEV u16 f2bf(float f) {
  unsigned u = __float_as_uint(f);
  unsigned r = (u + 0x7FFFu + ((u >> 16) & 1u)) >> 16;
  return (u16)r;
}
DEV float bf2f(u16 h) { return __uint_as_float((unsigned)h << 16); }
DEV unsigned pk(float lo, float hi) { return (unsigned)f2bf(lo) | ((unsigned)f2bf(hi) << 16); }

using gvoid = __attribute__((address_space(1))) const void;
using svoid = __attribute__((address_space(3))) void;
DEV void gl_lds16(const void* g, void* s) {
  __builtin_amdgcn_global_load_lds((gvoid*)g, (svoid*)s, 16, 0, 0);
}

// ---------------- transpose + cast f32 -> bf16 ----------------
// in: (batch, R, C) f32 ; out: (batch, C, R) bf16.  Requires R % 64 == 0.
__global__ __launch_bounds__(256) void k_transpose_cast(
    const float* __restrict__ in, u16* __restrict__ out, int R, int C) {
  __shared__ float tile[64][65];
  const int b = blockIdx.z;
  const int c0 = blockIdx.x * 64;
  const int r0 = blockIdx.y * 64;
  const float* inb = in + (size_t)b * R * C;
  u16* outb = out + (size_t)b * R * C;
  const int t = threadIdx.x;
  {
    const int rr = t >> 4;
    const int cq = (t & 15) * 4;
#pragma unroll
    for (int it = 0; it < 4; ++it) {
      int rl = rr + it * 16;
      int r = r0 + rl;
      int c = c0 + cq;
      if (c + 3 < C) {
        float4 v = *reinterpret_cast<const float4*>(&inb[(size_t)r * C + c]);
        tile[rl][cq + 0] = v.x; tile[rl][cq + 1] = v.y;
        tile[rl][cq + 2] = v.z; tile[rl][cq + 3] = v.w;
      } else {
#pragma unroll
        for (int j = 0; j < 4; ++j)
          tile[rl][cq + j] = (c + j < C) ? inb[(size_t)r * C + c + j] : 0.f;
      }
    }
  }
  __syncthreads();
  {
    const int c = t >> 2;
    const int rch = (t & 3) * 8;
    if (c0 + c < C) {
#pragma unroll
      for (int half = 0; half < 2; ++half) {
        int rb = rch + half * 32;
        uint4 o;
        o.x = pk(tile[rb + 0][c], tile[rb + 1][c]);
        o.y = pk(tile[rb + 2][c], tile[rb + 3][c]);
        o.z = pk(tile[rb + 4][c], tile[rb + 5][c]);
        o.w = pk(tile[rb + 6][c], tile[rb + 7][c]);
        *reinterpret_cast<uint4*>(&outb[(size_t)(c0 + c) * R + r0 + rb]) = o;
      }
    }
  }
}

// ---------------- ROI align: dedup taps + static-variant dispatch ----------------
DEV void acc8v(uint4 v, float w, float* a) {
  a[0] = fmaf(w, bf2f((u16)(v.x & 0xffffu)), a[0]);
  a[1] = fmaf(w, bf2f((u16)(v.x >> 16)), a[1]);
  a[2] = fmaf(w, bf2f((u16)(v.y & 0xffffu)), a[2]);
  a[3] = fmaf(w, bf2f((u16)(v.y >> 16)), a[3]);
  a[4] = fmaf(w, bf2f((u16)(v.z & 0xffffu)), a[4]);
  a[5] = fmaf(w, bf2f((u16)(v.z >> 16)), a[5]);
  a[6] = fmaf(w, bf2f((u16)(v.w & 0xffffu)), a[6]);
  a[7] = fmaf(w, bf2f((u16)(v.w >> 16)), a[7]);
}

// Fully-static tap loop: issue all YC*XC independent loads, then FMA.
// (Dedup guarantees YC,XC <= 3: sub-sample spacing = 0.5*ext/7 < 1 px.)
template <int YC, int XC>
DEV void bin_accum(const u16* bt, const int* yrow, const float* yw,
                   const int* xidx, const float* xw, float* a) {
  uint4 v[YC * XC];
#pragma unroll
  for (int jy = 0; jy < YC; ++jy)
#pragma unroll
    for (int jx = 0; jx < XC; ++jx)
      v[jy * XC + jx] =
          *reinterpret_cast<const uint4*>(bt + (size_t)(yrow[jy] + xidx[jx]) * CCH);
#pragma unroll
  for (int jy = 0; jy < YC; ++jy)
#pragma unroll
    for (int jx = 0; jx < XC; ++jx)
      acc8v(v[jy * XC + jx], yw[jy] * xw[jx], a);
}

__global__ __launch_bounds__(128) void k_roi_fast(
    const u16* __restrict__ fmT, const float* __restrict__ bboxes,
    const int* __restrict__ pfw, const int* __restrict__ pfh,
    u16* __restrict__ Aout) {
  const int r = blockIdx.x;   // roi 0..511
  const int py = blockIdx.y;  // bin row 0..6
  const int b = r >> 4;
  const int t = threadIdx.x;
  const int c0 = t * 8;

  __shared__ int s_cnt[2][7];
  __shared__ int s_idx[2][7][4];
  __shared__ float s_wgt[2][7][4];

  int axis = -1, p = 0;
  if (t < 7) { axis = 0; p = t; }
  else if (t >= 64 && t < 71) { axis = 1; p = t - 64; }
  if (axis >= 0) {
    float fwf = (float)pfw[0], fhf = (float)pfh[0];
    // reference: im_height = frame_width, im_width = frame_height
    float hs = (float)FHW / fwf;
    float wsc = (float)FHW / fhf;
    float v1 = bboxes[r * 4 + (axis == 0 ? 1 : 0)] * (axis == 0 ? hs : wsc);
    float v2 = bboxes[r * 4 + (axis == 0 ? 3 : 2)] * (axis == 0 ? hs : wsc);
    float ext = fmaxf(v2 - v1, 1.0f);
    int idx[4]; float wgt[4]; int cnt = 0;
#pragma unroll
    for (int j = 0; j < 2; ++j) {
      float g = (float)p + (j ? 0.75f : 0.25f);
      float coord = v1 + (ext / 7.0f) * g;
      float valid = (coord >= -1.0f && coord <= 50.0f) ? 1.0f : 0.0f;
      float cc = fmaxf(coord, 0.0f);
      int lo = (int)floorf(cc);
      bool edge = (lo >= FHW - 1);
      lo = min(lo, FHW - 1);
      int hi = min(lo + 1, FHW - 1);
      float l = edge ? 0.0f : (cc - (float)lo);
      float pr_i[2]; int pr_x[2];
      pr_x[0] = lo; pr_i[0] = valid * (1.0f - l);
      pr_x[1] = hi; pr_i[1] = valid * l;
#pragma unroll
      for (int e = 0; e < 2; ++e) {
        if (pr_i[e] != 0.0f) {
          bool found = false;
          for (int q = 0; q < cnt; ++q)
            if (idx[q] == pr_x[e]) { wgt[q] += pr_i[e]; found = true; }
          if (!found) { idx[cnt] = pr_x[e]; wgt[cnt] = pr_i[e]; ++cnt; }
        }
      }
    }
    s_cnt[axis][p] = cnt;
#pragma unroll
    for (int q = 0; q < 4; ++q) {
      s_idx[axis][p][q] = (q < cnt) ? idx[q] : 0;
      s_wgt[axis][p][q] = (q < cnt) ? wgt[q] : 0.0f;
    }
  }
  __syncthreads();

  const u16* bt = fmT + (size_t)b * HW * CCH + c0;

  // hoist y-list for this py (register arrays, static-indexed below)
  const int ycnt = s_cnt[0][py];
  int yrow[3]; float yw[3];
#pragma unroll
  for (int q = 0; q < 3; ++q) {
    yrow[q] = s_idx[0][py][q] * FHW;
    yw[q] = s_wgt[0][py][q];
  }

  for (int px = 0; px < 7; ++px) {
    const int xcnt = s_cnt[1][px];
    int xidx[3]; float xw[3];
#pragma unroll
    for (int q = 0; q < 3; ++q) {
      xidx[q] = s_idx[1][px][q];
      xw[q] = s_wgt[1][px][q];
    }
    float a[8] = {};
    // wave-uniform dispatch to fully-static tap loops (cnt <= 3 guaranteed)
    switch (ycnt * 4 + xcnt) {
      case 1 * 4 + 1: bin_accum<1, 1>(bt, yrow, yw, xidx, xw, a); break;
      case 1 * 4 + 2: bin_accum<1, 2>(bt, yrow, yw, xidx, xw, a); break;
      case 1 * 4 + 3: bin_accum<1, 3>(bt, yrow, yw, xidx, xw, a); break;
      case 2 * 4 + 1: bin_accum<2, 1>(bt, yrow, yw, xidx, xw, a); break;
      case 2 * 4 + 2: bin_accum<2, 2>(bt, yrow, yw, xidx, xw, a); break;
      case 2 * 4 + 3: bin_accum<2, 3>(bt, yrow, yw, xidx, xw, a); break;
      case 3 * 4 + 1: bin_accum<3, 1>(bt, yrow, yw, xidx, xw, a); break;
      case 3 * 4 + 2: bin_accum<3, 2>(bt, yrow, yw, xidx, xw, a); break;
      case 3 * 4 + 3: bin_accum<3, 3>(bt, yrow, yw, xidx, xw, a); break;
      default: break;  // cnt==0 on some axis -> bin is all zeros
    }
    u16* dst = Aout + (size_t)(r * 49 + py * 7 + px) * CCH + c0;
    uint4 o;
    o.x = pk(a[0] * 0.25f, a[1] * 0.25f);
    o.y = pk(a[2] * 0.25f, a[3] * 0.25f);
    o.z = pk(a[4] * 0.25f, a[5] * 0.25f);
    o.w = pk(a[6] * 0.25f, a[7] * 0.25f);
    *reinterpret_cast<uint4*>(dst) = o;
  }
}

// ---------------- GEMM (m97 structure, proven): Out = relu(A @ Bt^T + bias) ---
// A: (M,K) bf16 row-major.  Bt: (N,K) bf16 row-major.
// 128x128 tile, BK=32, 4 waves (2x2), 4x4 16x16 frags/wave.
// 1D grid, XCD-chunked swizzle (gridDim.x % 8 == 0), n-tile fastest.
template <int K, int N, int OBF>
__global__ __launch_bounds__(256) void k_gemm(
    const u16* __restrict__ A, const u16* __restrict__ Bt,
    const float* __restrict__ bias, void* __restrict__ Out) {
  __shared__ alignas(16) u16 As[128 * 32];
  __shared__ alignas(16) u16 Bs[128 * 32];
  const int t = threadIdx.x;
  const int lane = t & 63, w = t >> 6;
  const int wr = w >> 1, wc = w & 1;
  const int NT = N / 128;
  const int bid = blockIdx.x;
  const int chunk = (int)(gridDim.x >> 3);
  const int swz = (bid & 7) * chunk + (bid >> 3);
  const size_t m0 = (size_t)(swz / NT) * 128;
  const int n0 = (swz % NT) * 128;
  f32x4 acc[4][4] = {};
  const int srow = t >> 2;
  const int skc = (t & 3) * 8;
  for (int ks = 0; ks < K / 32; ++ks) {
    const int k0 = ks * 32;
    if (ks) __syncthreads();
    gl_lds16(A + (m0 + srow) * K + k0 + skc, &As[(size_t)t * 8]);
    gl_lds16(A + (m0 + 64 + srow) * K + k0 + skc, &As[(size_t)(t + 256) * 8]);
    gl_lds16(Bt + (size_t)(n0 + srow) * K + k0 + skc, &Bs[(size_t)t * 8]);
    gl_lds16(Bt + (size_t)(n0 + 64 + srow) * K + k0 + skc, &Bs[(size_t)(t + 256) * 8]);
    __syncthreads();
    const int koff = (lane >> 4) * 8;
    bf16x8 av[4], bv[4];
#pragma unroll
    for (int m = 0; m < 4; ++m)
      av[m] = *reinterpret_cast<const bf16x8*>(&As[(wr * 64 + m * 16 + (lane & 15)) * 32 + koff]);
#pragma unroll
    for (int n = 0; n < 4; ++n)
      bv[n] = *reinterpret_cast<const bf16x8*>(&Bs[(wc * 64 + n * 16 + (lane & 15)) * 32 + koff]);
#pragma unroll
    for (int m = 0; m < 4; ++m)
#pragma unroll
      for (int n = 0; n < 4; ++n)
        asm("v_mfma_f32_16x16x32_bf16 %0, %1, %2, %0"
            : "+v"(acc[m][n]) : "v"(av[m]), "v"(bv[n]));
  }
  asm volatile("s_nop 7\n\ts_nop 7\n\ts_nop 7" ::);
#pragma unroll
  for (int n = 0; n < 4; ++n) {
    int col = n0 + wc * 64 + n * 16 + (lane & 15);
    float bb = bias[col];
#pragma unroll
    for (int m = 0; m < 4; ++m) {
      size_t row0 = m0 + wr * 64 + m * 16 + (lane >> 4) * 4;
#pragma unroll
      for (int qq = 0; qq < 4; ++qq) {
        float v = fmaxf(acc[m][n][qq] + bb, 0.0f);
        if (OBF) ((u16*)Out)[(row0 + qq) * N + col] = f2bf(v);
        else     ((float*)Out)[(row0 + qq) * N + col] = v;
      }
    }
  }
}

// ---------------- mean over 49 bins (bf16 input) ----------------
__global__ __launch_bounds__(256) void k_mean(const u16* __restrict__ H2,
                                              float* __restrict__ feat) {
  const int r = blockIdx.x;
  const int c = threadIdx.x * 2;
  float s0 = 0.f, s1 = 0.f;
#pragma unroll
  for (int qq = 0; qq < 49; ++qq) {
    unsigned v = *reinterpret_cast<const unsigned*>(&H2[((size_t)r * 49 + qq) * D2 + c]);
    s0 += bf2f((u16)(v & 0xffffu));
    s1 += bf2f((u16)(v >> 16));
  }
  feat[(size_t)r * D2 + c] = s0 * (1.0f / 49.0f);
  feat[(size_t)r * D2 + c + 1] = s1 * (1.0f / 49.0f);
}

// ---------------- pair gather ----------------
__global__ __launch_bounds__(256) void k_pairs(
    const float* __restrict__ feat, const int* __restrict__ num_obj,
    const int* __restrict__ pairs, float* __restrict__ out) {
  int r = blockIdx.x;
  int b = r >> 6;
  int off = 0;
  for (int i = 0; i < b; ++i) off += num_obj[i];
  int g0 = off + pairs[r * 2 + 0];
  int g1 = off + pairs[r * 2 + 1];
  for (int c = threadIdx.x; c < D2; c += 256) {
    out[(size_t)r * D2 + c] = 0.5f * (feat[(size_t)g0 * D2 + c] + feat[(size_t)g1 * D2 + c]);
  }
}

extern "C" void kernel_launch(void* const* d_in, const int* in_sizes, int n_in,
                              void* d_out, int out_size, void* d_ws, size_t ws_size,
                              hipStream_t stream) {
  const float* fmap = (const float*)d_in[0];
  const float* bboxes = (const float*)d_in[1];
  const int* num_obj = (const int*)d_in[2];
  const int* obj_pairs = (const int*)d_in[3];
  const int* pfw = (const int*)d_in[5];
  const int* pfh = (const int*)d_in[6];
  const float* W1 = (const float*)d_in[7];
  const float* b1 = (const float*)d_in[8];
  const float* W2 = (const float*)d_in[9];
  const float* b2 = (const float*)d_in[10];
  float* out = (float*)d_out;

  const size_t SZ_FMT = (size_t)BB * HW * CCH * 2;
  const size_t SZ_A   = (size_t)MROWS * D1 * 2;
  const size_t SZ_H1  = (size_t)MROWS * D1 * 2;
  const size_t SZ_W1B = (size_t)D1 * D1 * 2;
  const size_t SZ_W2B = (size_t)D1 * D2 * 2;

  char* ws = (char*)d_ws;
  u16 *fmT, *A, *H1, *W1b, *W2b, *H2b;
  float *feat;
  fmT = (u16*)ws;
  A = (u16*)(ws + SZ_FMT);
  H1 = (u16*)(ws + SZ_FMT + SZ_A);
  W1b = (u16*)(ws + SZ_FMT + SZ_A + SZ_H1);
  W2b = (u16*)(ws + SZ_FMT + SZ_A + SZ_H1 + SZ_W1B);
  feat = (float*)(ws + SZ_FMT + SZ_A + SZ_H1 + SZ_W1B + SZ_W2B);
  H2b = fmT;  // fmT dead after ROI align

  // weight transposes (K,N)->(N,K) bf16
  k_transpose_cast<<<dim3(16, 16, 1), 256, 0, stream>>>(W1, W1b, D1, D1);
  k_transpose_cast<<<dim3(8, 16, 1), 256, 0, stream>>>(W2, W2b, D1, D2);

  // fmap (B, C=1024, HW=2500) -> (B, HW, C) bf16
  k_transpose_cast<<<dim3(40, 16, BB), 256, 0, stream>>>(fmap, fmT, CCH, HW);
  k_roi_fast<<<dim3(NROI, 7), 128, 0, stream>>>(fmT, bboxes, pfw, pfh, A);

  k_gemm<D1, D1, 1><<<(MROWS / 128) * (D1 / 128), 256, 0, stream>>>(A, W1b, b1, (void*)H1);
  k_gemm<D1, D2, 1><<<(MROWS / 128) * (D2 / 128), 256, 0, stream>>>(H1, W2b, b2, (void*)H2b);
  k_mean<<<NROI, 256, 0, stream>>>(H2b, feat);
  k_pairs<<<BB * NREL, 256, 0, stream>>>(feat, num_obj, obj_pairs, out);
}